// Round 21
// baseline (256.028 us; speedup 1.0000x reference)
//
#include <hip/hip_runtime.h>
#include <math.h>

// LSTMLightweight on MI355X (R21 = R20 + LDS lookup-table activations).
//   x[B,T,1] -> linear_in(1->16)+ReLU -> LSTM0(16) -> LSTM1(16) -> fc(16->8)+ReLU -> fc(8->1)
// R20 issue model (closes against counters): occupied SIMDs 87% issue-bound;
// 80 trans/step (sigm/tanh = 2 v_exp/v_rcp each) at ~16 cyc issue-occupancy
// each = 1280 of the 1780 cyc/step. R18's packed-FMA replacement failed by
// costing MORE issue; R21 replaces each activation with an LDS lerp-table
// lookup: ~8 full-rate VALU + 1 ds_read_b64 (DS pipe is otherwise idle here,
// so the reads hide under VALU issue). Tables: 2048 x float2 (value, delta)
// over [-16,16), h=1/64 -> lerp err ~3e-6, clamp err ~1e-7 (vs 1.95e-3 f16
// floor). Built once per block; LDS 33KB (2 blocks/CU fine).
// Everything else identical to R20: f16 2-product MFMA (B-side split),
// K-permuted A so B is lane-local (k=8g+i -> W_ih[.][4g+i] | W_hh[.][4g+i-4];
// D row=4*(lane>>4)+q, col=lane&15), bias in C-init, L1(t)||L0(t+1) pipeline.

#define L2E 1.4426950408889634f
#define EPB 16        // elements per wave (= MFMA N)
#define LUTN 2048
#define LUTH 0.015625f        // 1/64
#define LUTMAX 15.984375f     // 16 - h

typedef _Float16 f16x8 __attribute__((ext_vector_type(8)));
typedef float    f32x4 __attribute__((ext_vector_type(4)));

__device__ __forceinline__ float sigm(float v) {
    return __builtin_amdgcn_rcpf(1.0f + __builtin_amdgcn_exp2f(-L2E * v));
}
__device__ __forceinline__ float tanh_(float v) {
    // tanh(v) = 1 - 2/(exp(2v)+1); saturates correctly at +-inf
    return 1.0f - 2.0f * __builtin_amdgcn_rcpf(1.0f + __builtin_amdgcn_exp2f((2.0f * L2E) * v));
}

// table lookup with linear interpolation; tab[i] = (f(xi), f(xi+h)-f(xi))
__device__ __forceinline__ float lut(const float2* tab, float v) {
    const float vc = fminf(fmaxf(v, -16.0f), LUTMAX);
    const float t  = fmaf(vc, 64.0f, 1024.0f);      // (vc+16)/h
    const int   idx = (int)t;                       // 0..2047 (t >= 0)
    const float d  = t - (float)idx;                // frac in [0,1)
    const float2 e = tab[idx];
    return fmaf(e.y, d, e.x);
}

// split a float into f16 hi (RTN cast) + f16 lo (residual)
#define SPLIT4(V, FH, FL)                                         \
    _Pragma("unroll")                                             \
    for (int i_ = 0; i_ < 4; ++i_) {                              \
        const _Float16 hh_ = (_Float16)V[i_];                     \
        FH[i_] = hh_;                                             \
        FL[i_] = (_Float16)(V[i_] - (float)hh_);                  \
    }

__device__ __forceinline__ f16x8 mk8(const _Float16* a, const _Float16* b) {
    f16x8 r;
    #pragma unroll
    for (int i = 0; i < 4; ++i) { r[i] = a[i]; r[4 + i] = b[i]; }
    return r;
}

// one layer's gates: acc[m] = bias[m] + Ahi·Bl + Ahi·Bh   (2 MFMAs/tile)
#define GATES16(ACC, AHI, BIAS, BH, BL)                                               \
    _Pragma("unroll")                                                                 \
    for (int m = 0; m < 4; ++m) {                                                     \
        ACC[m] = BIAS[m];                                                             \
        ACC[m] = __builtin_amdgcn_mfma_f32_16x16x32_f16(AHI[m], BL, ACC[m], 0, 0, 0); \
        ACC[m] = __builtin_amdgcn_mfma_f32_16x16x32_f16(AHI[m], BH, ACC[m], 0, 0, 0); \
    }

// combine via LUT: i,f,g,o -> c,h (per q); writes HV[4], updates CC[4]
#define COMBINE_LUT(ACC, CC, HV)                                                      \
    _Pragma("unroll")                                                                 \
    for (int q = 0; q < 4; ++q) {                                                     \
        const float ig_ = lut(stab, ACC[0][q]);                                       \
        const float fg_ = lut(stab, ACC[1][q]);                                       \
        const float gv_ = lut(ttab, ACC[2][q]);                                       \
        const float og_ = lut(stab, ACC[3][q]);                                       \
        CC[q] = fmaf(fg_, CC[q], ig_ * gv_);                                          \
        HV[q] = og_ * lut(ttab, CC[q]);                                               \
    }

__global__ __launch_bounds__(64) void lstm_lut(
    const float* __restrict__ x,
    const float* __restrict__ w_in, const float* __restrict__ b_in,
    const float* __restrict__ w_ih0, const float* __restrict__ w_hh0,
    const float* __restrict__ b_ih0, const float* __restrict__ b_hh0,
    const float* __restrict__ w_ih1, const float* __restrict__ w_hh1,
    const float* __restrict__ b_ih1, const float* __restrict__ b_hh1,
    const float* __restrict__ fc_h_w, const float* __restrict__ fc_h_b,
    const float* __restrict__ fc_o_w, const float* __restrict__ fc_o_b,
    float* __restrict__ out, int B, int T)
{
    const int lane = threadIdx.x;        // 0..63
    const int e    = lane & 15;          // element column (= A row within tile)
    const int g    = lane >> 4;          // k-group / D-row group
    const int base = blockIdx.x * EPB;
    int rowe = base + e; if (rowe >= B) rowe = B - 1;

    __shared__ float2 stab[LUTN];        // sigmoid table (16 KB)
    __shared__ float2 ttab[LUTN];        // tanh table    (16 KB)
    __shared__ float  htab[EPB][16];     // head exchange (1 KB)

    // ---- build activation tables (once per block; trans ops off hot path) ----
    for (int i = lane; i < LUTN; i += 64) {
        const float xv = -16.0f + i * LUTH;
        const float s0 = sigm(xv), s1 = sigm(xv + LUTH);
        stab[i] = make_float2(s0, s1 - s0);
        const float t0 = tanh_(xv), t1 = tanh_(xv + LUTH);
        ttab[i] = make_float2(t0, t1 - t0);
    }

    // ---- A-fragments (f16 RTN, single plane), K-permuted ----
    f16x8 a0[4], a1[4];
    f32x4 bias0[4], bias1[4];
    #pragma unroll
    for (int m = 0; m < 4; ++m) {
        const int r = 16 * m + e;
        #pragma unroll
        for (int i = 0; i < 8; ++i) {
            const float w0 = (i < 4) ? w_ih0[r * 16 + 4 * g + i]
                                     : w_hh0[r * 16 + 4 * g + (i - 4)];
            const float w1 = (i < 4) ? w_ih1[r * 16 + 4 * g + i]
                                     : w_hh1[r * 16 + 4 * g + (i - 4)];
            a0[m][i] = (_Float16)w0;
            a1[m][i] = (_Float16)w1;
        }
        const int rd = 16 * m + 4 * g;
        #pragma unroll
        for (int q = 0; q < 4; ++q) {
            bias0[m][q] = b_ih0[rd + q] + b_hh0[rd + q];
            bias1[m][q] = b_ih1[rd + q] + b_hh1[rd + q];
        }
    }
    float winq[4], binq[4];
    #pragma unroll
    for (int q = 0; q < 4; ++q) { winq[q] = w_in[4 * g + q]; binq[q] = b_in[4 * g + q]; }

    __syncthreads();                     // tables ready

    // ---- state: c in f32; h kept as f16 hi/lo element arrays ----
    float c0[4] = {0.f, 0.f, 0.f, 0.f};
    float c1[4] = {0.f, 0.f, 0.f, 0.f};
    float h1v[4] = {0.f, 0.f, 0.f, 0.f};
    _Float16 h0h[4], h0l[4], h1h[4], h1l[4];
    #pragma unroll
    for (int q = 0; q < 4; ++q) { h1h[q] = (_Float16)0.f; h1l[q] = (_Float16)0.f; }

    const float* xrow = x + (size_t)rowe * T;

    // ---- prologue: L0 at t=0 (h0_{-1}=0) ----
    {
        const float xv = xrow[0];
        float xq[4];
        #pragma unroll
        for (int q = 0; q < 4; ++q) xq[q] = fmaxf(fmaf(xv, winq[q], binq[q]), 0.0f);
        _Float16 xh[4], xl[4], zh[4];
        SPLIT4(xq, xh, xl);
        #pragma unroll
        for (int q = 0; q < 4; ++q) zh[q] = (_Float16)0.f;
        const f16x8 Bh = mk8(xh, zh);
        const f16x8 Bl = mk8(xl, zh);
        f32x4 acc[4];
        GATES16(acc, a0, bias0, Bh, Bl);
        float h0v[4];
        COMBINE_LUT(acc, c0, h0v);
        SPLIT4(h0v, h0h, h0l);
    }

    float xv1 = xrow[(T > 1) ? 1 : 0];               // x(t+1) for the loop

    // ---- steady state: iteration t does L1(t) || L0(t+1) (independent) ----
    for (int t = 0; t < T - 1; ++t) {
        const int tn = (t + 2 < T) ? (t + 2) : (T - 1);
        const float xn = xrow[tn];                   // prefetch x(t+2)

        float xq[4];
        #pragma unroll
        for (int q = 0; q < 4; ++q) xq[q] = fmaxf(fmaf(xv1, winq[q], binq[q]), 0.0f);
        _Float16 xh[4], xl[4];
        SPLIT4(xq, xh, xl);

        const f16x8 B0h = mk8(xh, h0h);              // [xi(t+1); h0(t)]
        const f16x8 B0l = mk8(xl, h0l);
        const f16x8 B1h = mk8(h0h, h1h);             // [h0(t); h1(t-1)]
        const f16x8 B1l = mk8(h0l, h1l);

        f32x4 acc0[4], acc1[4];
        GATES16(acc0, a0, bias0, B0h, B0l);          // L0(t+1)
        GATES16(acc1, a1, bias1, B1h, B1l);          // L1(t)

        float h0v[4];
        COMBINE_LUT(acc0, c0, h0v);                  // h0(t+1)
        COMBINE_LUT(acc1, c1, h1v);                  // h1(t)

        SPLIT4(h0v, h0h, h0l);
        SPLIT4(h1v, h1h, h1l);
        xv1 = xn;
    }

    // ---- epilogue: L1(T-1) from h0(T-1), h1(T-2) ----
    {
        const f16x8 Bh = mk8(h0h, h1h);
        const f16x8 Bl = mk8(h0l, h1l);
        f32x4 acc[4];
        GATES16(acc, a1, bias1, Bh, Bl);
        COMBINE_LUT(acc, c1, h1v);                   // final h1
    }

    // ---- head: fc_h (16->8) + ReLU, fc_o (8->1) ----
    *(float4*)&htab[e][4 * g] = make_float4(h1v[0], h1v[1], h1v[2], h1v[3]);
    __syncthreads();
    if (lane < EPB) {
        const int ee = lane;
        float hv[16];
        #pragma unroll
        for (int k = 0; k < 16; ++k) hv[k] = htab[ee][k];
        float z[8];
        #pragma unroll
        for (int p = 0; p < 8; ++p) {
            float acc = fc_h_b[p];
            #pragma unroll
            for (int k = 0; k < 16; ++k) acc = fmaf(fc_h_w[p * 16 + k], hv[k], acc);
            z[p] = fmaxf(acc, 0.0f);
        }
        float o = fc_o_b[0];
        #pragma unroll
        for (int p = 0; p < 8; ++p) o = fmaf(fc_o_w[p], z[p], o);
        if (base + ee < B) out[base + ee] = o;
    }
}

extern "C" void kernel_launch(void* const* d_in, const int* in_sizes, int n_in,
                              void* d_out, int out_size, void* d_ws, size_t ws_size,
                              hipStream_t stream) {
    const float* x      = (const float*)d_in[0];
    const float* w_in   = (const float*)d_in[1];
    const float* b_in   = (const float*)d_in[2];
    const float* w_ih0  = (const float*)d_in[3];
    const float* w_hh0  = (const float*)d_in[4];
    const float* b_ih0  = (const float*)d_in[5];
    const float* b_hh0  = (const float*)d_in[6];
    const float* w_ih1  = (const float*)d_in[7];
    const float* w_hh1  = (const float*)d_in[8];
    const float* b_ih1  = (const float*)d_in[9];
    const float* b_hh1  = (const float*)d_in[10];
    const float* fc_h_w = (const float*)d_in[11];
    const float* fc_h_b = (const float*)d_in[12];
    const float* fc_o_w = (const float*)d_in[13];
    const float* fc_o_b = (const float*)d_in[14];

    const int B = out_size;                 // x is [B,T,1]
    const int T = in_sizes[0] / (B > 0 ? B : 1);
    const int grid = (B + EPB - 1) / EPB;   // 512 blocks at B=8192

    hipLaunchKernelGGL(lstm_lut, dim3(grid), dim3(64), 0, stream,
                       x, w_in, b_in, w_ih0, w_hh0, b_ih0, b_hh0,
                       w_ih1, w_hh1, b_ih1, b_hh1, fc_h_w, fc_h_b,
                       fc_o_w, fc_o_b, (float*)d_out, B, T);
}

// Round 22
// 163.832 us; speedup vs baseline: 1.5628x; 1.5628x over previous
//
#include <hip/hip_runtime.h>
#include <math.h>

// LSTMLightweight on MI355X (R22 = R20 + fraction-combined activations + single-product f16 MFMA).
//   x[B,T,1] -> linear_in(1->16)+ReLU -> LSTM0(16) -> LSTM1(16) -> fc(16->8)+ReLU -> fc(8->1)
// Ledger: R20 (190us) is ~pure issue-bound: 80 trans x 16cyc + ~240 VALU x 2
// + 16 MFMA x 5 ~= 1780 cyc/step. R21 (LUT) died on DS latency in the c-chain;
// R18 showed v2f does NOT lower to packed ops (poly issued MORE than trans).
// R22 cuts issue two ways:
//  (1) fraction-combined gates: i*g = (1-Eg)/((1+Ei)(1+Eg)),
//      o*tanh(c) = (1-Ec)/((1+Eo)(1+Ec)) -> 8 trans/unit instead of 10,
//      NaN-safe with two one-sided clamps (rcp(inf)=0 paths end finite*0).
//  (2) B-side lo split dropped: xi/h as plain f16 RTN -> 8 MFMAs/step (not 16),
//      no SPLIT-lo, no Bl packs. Adds ~2.4e-4/step quantization; predicted
//      absmax 2-5e-3 < 9.1e-3 threshold (revert if it blows).
// Rest identical to R20: K-permuted A so B is lane-local (k=8g+i ->
// W_ih[.][4g+i] | W_hh[.][4g+i-4]; D row=4*(lane>>4)+q, col=lane&15),
// bias in C-init, L1(t) || L0(t+1) in-wave pipeline.

#define L2E 1.4426950408889634f
#define EPB 16        // elements per wave (= MFMA N)

typedef _Float16 f16x8 __attribute__((ext_vector_type(8)));
typedef float    f32x4 __attribute__((ext_vector_type(4)));

__device__ __forceinline__ float sigm(float v) {
    return __builtin_amdgcn_rcpf(1.0f + __builtin_amdgcn_exp2f(-L2E * v));
}
__device__ __forceinline__ float tanh_(float v) {
    return 1.0f - 2.0f * __builtin_amdgcn_rcpf(1.0f + __builtin_amdgcn_exp2f((2.0f * L2E) * v));
}

__device__ __forceinline__ f16x8 mk8(const _Float16* a, const _Float16* b) {
    f16x8 r;
    #pragma unroll
    for (int i = 0; i < 4; ++i) { r[i] = a[i]; r[4 + i] = b[i]; }
    return r;
}

// one layer's gates, single product: acc[m] = bias[m] + A·Bh
#define GATES1(ACC, A, BIAS, BH)                                                      \
    _Pragma("unroll")                                                                 \
    for (int m = 0; m < 4; ++m) {                                                     \
        ACC[m] = BIAS[m];                                                             \
        ACC[m] = __builtin_amdgcn_mfma_f32_16x16x32_f16(A[m], BH, ACC[m], 0, 0, 0);   \
    }

// fraction-combined LSTM cell update (8 trans/unit instead of 10):
//   Ei=e^-ai, Ef=e^-af, Eg=e^-2ag (clamped), Eo=e^-ao, Ec=e^-2c (clamped)
//   f = 1/(1+Ef); i*g = (1-Eg)/((1+Ei)(1+Eg)); c = f*c + i*g
//   h = o*tanh(c) = (1-Ec)/((1+Eo)(1+Ec))
#define COMBINE_FR(ACC, CC, HV)                                                       \
    _Pragma("unroll")                                                                 \
    for (int q = 0; q < 4; ++q) {                                                     \
        const float Ei_ = __builtin_amdgcn_exp2f(-L2E * ACC[0][q]);                   \
        const float Ef_ = __builtin_amdgcn_exp2f(-L2E * ACC[1][q]);                   \
        const float Eg_ = __builtin_amdgcn_exp2f(fmaxf(ACC[2][q], -40.0f) *           \
                                                 (-2.0f * L2E));                      \
        const float Eo_ = __builtin_amdgcn_exp2f(-L2E * ACC[3][q]);                   \
        const float fg_ = __builtin_amdgcn_rcpf(1.0f + Ef_);                          \
        const float ig_ = (1.0f - Eg_) *                                              \
            __builtin_amdgcn_rcpf((1.0f + Ei_) * (1.0f + Eg_));                       \
        CC[q] = fmaf(fg_, CC[q], ig_);                                                \
        const float Ec_ = __builtin_amdgcn_exp2f(fmaxf(CC[q], -40.0f) *               \
                                                 (-2.0f * L2E));                      \
        HV[q] = (1.0f - Ec_) *                                                        \
            __builtin_amdgcn_rcpf((1.0f + Eo_) * (1.0f + Ec_));                       \
    }

__global__ __launch_bounds__(64) void lstm_fr(
    const float* __restrict__ x,
    const float* __restrict__ w_in, const float* __restrict__ b_in,
    const float* __restrict__ w_ih0, const float* __restrict__ w_hh0,
    const float* __restrict__ b_ih0, const float* __restrict__ b_hh0,
    const float* __restrict__ w_ih1, const float* __restrict__ w_hh1,
    const float* __restrict__ b_ih1, const float* __restrict__ b_hh1,
    const float* __restrict__ fc_h_w, const float* __restrict__ fc_h_b,
    const float* __restrict__ fc_o_w, const float* __restrict__ fc_o_b,
    float* __restrict__ out, int B, int T)
{
    const int lane = threadIdx.x;        // 0..63
    const int e    = lane & 15;          // element column (= A row within tile)
    const int g    = lane >> 4;          // k-group / D-row group
    const int base = blockIdx.x * EPB;
    int rowe = base + e; if (rowe >= B) rowe = B - 1;

    __shared__ float htab[EPB][16];      // head exchange only

    // ---- A-fragments (f16 RTN), K-permuted ----
    f16x8 a0[4], a1[4];
    f32x4 bias0[4], bias1[4];
    #pragma unroll
    for (int m = 0; m < 4; ++m) {
        const int r = 16 * m + e;
        #pragma unroll
        for (int i = 0; i < 8; ++i) {
            const float w0 = (i < 4) ? w_ih0[r * 16 + 4 * g + i]
                                     : w_hh0[r * 16 + 4 * g + (i - 4)];
            const float w1 = (i < 4) ? w_ih1[r * 16 + 4 * g + i]
                                     : w_hh1[r * 16 + 4 * g + (i - 4)];
            a0[m][i] = (_Float16)w0;
            a1[m][i] = (_Float16)w1;
        }
        const int rd = 16 * m + 4 * g;
        #pragma unroll
        for (int q = 0; q < 4; ++q) {
            bias0[m][q] = b_ih0[rd + q] + b_hh0[rd + q];
            bias1[m][q] = b_ih1[rd + q] + b_hh1[rd + q];
        }
    }
    float winq[4], binq[4];
    #pragma unroll
    for (int q = 0; q < 4; ++q) { winq[q] = w_in[4 * g + q]; binq[q] = b_in[4 * g + q]; }

    // ---- state: c in f32; h as f16 (RTN) element arrays ----
    float c0[4] = {0.f, 0.f, 0.f, 0.f};
    float c1[4] = {0.f, 0.f, 0.f, 0.f};
    float h1v[4] = {0.f, 0.f, 0.f, 0.f};
    _Float16 h0h[4], h1h[4];
    #pragma unroll
    for (int q = 0; q < 4; ++q) h1h[q] = (_Float16)0.f;

    const float* xrow = x + (size_t)rowe * T;

    // ---- prologue: L0 at t=0 (h0_{-1}=0) ----
    {
        const float xv = xrow[0];
        _Float16 xh[4], zh[4];
        #pragma unroll
        for (int q = 0; q < 4; ++q) {
            xh[q] = (_Float16)fmaxf(fmaf(xv, winq[q], binq[q]), 0.0f);
            zh[q] = (_Float16)0.f;
        }
        const f16x8 Bh = mk8(xh, zh);
        f32x4 acc[4];
        GATES1(acc, a0, bias0, Bh);
        float h0v[4];
        COMBINE_FR(acc, c0, h0v);
        #pragma unroll
        for (int q = 0; q < 4; ++q) h0h[q] = (_Float16)h0v[q];
    }

    float xv1 = xrow[(T > 1) ? 1 : 0];               // x(t+1) for the loop

    // ---- steady state: iteration t does L1(t) || L0(t+1) (independent) ----
    for (int t = 0; t < T - 1; ++t) {
        const int tn = (t + 2 < T) ? (t + 2) : (T - 1);
        const float xn = xrow[tn];                   // prefetch x(t+2)

        _Float16 xh[4];
        #pragma unroll
        for (int q = 0; q < 4; ++q)
            xh[q] = (_Float16)fmaxf(fmaf(xv1, winq[q], binq[q]), 0.0f);

        const f16x8 B0h = mk8(xh, h0h);              // [xi(t+1); h0(t)]
        const f16x8 B1h = mk8(h0h, h1h);             // [h0(t); h1(t-1)]

        f32x4 acc0[4], acc1[4];
        GATES1(acc0, a0, bias0, B0h);                // L0(t+1)
        GATES1(acc1, a1, bias1, B1h);                // L1(t)

        float h0v[4];
        COMBINE_FR(acc0, c0, h0v);                   // h0(t+1)
        COMBINE_FR(acc1, c1, h1v);                   // h1(t)

        #pragma unroll
        for (int q = 0; q < 4; ++q) {
            h0h[q] = (_Float16)h0v[q];
            h1h[q] = (_Float16)h1v[q];
        }
        xv1 = xn;
    }

    // ---- epilogue: L1(T-1) from h0(T-1), h1(T-2) ----
    {
        const f16x8 Bh = mk8(h0h, h1h);
        f32x4 acc[4];
        GATES1(acc, a1, bias1, Bh);
        COMBINE_FR(acc, c1, h1v);                    // final h1
    }

    // ---- head: fc_h (16->8) + ReLU, fc_o (8->1) ----
    *(float4*)&htab[e][4 * g] = make_float4(h1v[0], h1v[1], h1v[2], h1v[3]);
    __syncthreads();
    if (lane < EPB) {
        const int ee = lane;
        float hv[16];
        #pragma unroll
        for (int k = 0; k < 16; ++k) hv[k] = htab[ee][k];
        float z[8];
        #pragma unroll
        for (int p = 0; p < 8; ++p) {
            float acc = fc_h_b[p];
            #pragma unroll
            for (int k = 0; k < 16; ++k) acc = fmaf(fc_h_w[p * 16 + k], hv[k], acc);
            z[p] = fmaxf(acc, 0.0f);
        }
        float o = fc_o_b[0];
        #pragma unroll
        for (int p = 0; p < 8; ++p) o = fmaf(fc_o_w[p], z[p], o);
        if (base + ee < B) out[base + ee] = o;
    }
}

extern "C" void kernel_launch(void* const* d_in, const int* in_sizes, int n_in,
                              void* d_out, int out_size, void* d_ws, size_t ws_size,
                              hipStream_t stream) {
    const float* x      = (const float*)d_in[0];
    const float* w_in   = (const float*)d_in[1];
    const float* b_in   = (const float*)d_in[2];
    const float* w_ih0  = (const float*)d_in[3];
    const float* w_hh0  = (const float*)d_in[4];
    const float* b_ih0  = (const float*)d_in[5];
    const float* b_hh0  = (const float*)d_in[6];
    const float* w_ih1  = (const float*)d_in[7];
    const float* w_hh1  = (const float*)d_in[8];
    const float* b_ih1  = (const float*)d_in[9];
    const float* b_hh1  = (const float*)d_in[10];
    const float* fc_h_w = (const float*)d_in[11];
    const float* fc_h_b = (const float*)d_in[12];
    const float* fc_o_w = (const float*)d_in[13];
    const float* fc_o_b = (const float*)d_in[14];

    const int B = out_size;                 // x is [B,T,1]
    const int T = in_sizes[0] / (B > 0 ? B : 1);
    const int grid = (B + EPB - 1) / EPB;   // 512 blocks at B=8192

    hipLaunchKernelGGL(lstm_fr, dim3(grid), dim3(64), 0, stream,
                       x, w_in, b_in, w_ih0, w_hh0, b_ih0, b_hh0,
                       w_ih1, w_hh1, b_ih1, b_hh1, fc_h_w, fc_h_b,
                       fc_o_w, fc_o_b, (float*)d_out, B, T);
}

// Round 23
// 154.126 us; speedup vs baseline: 1.6612x; 1.0630x over previous
//
#include <hip/hip_runtime.h>
#include <math.h>

// LSTMLightweight on MI355X (R23 = R22 + one-rcp cell update).
//   x[B,T,1] -> linear_in(1->16)+ReLU -> LSTM0(16) -> LSTM1(16) -> fc(16->8)+ReLU -> fc(8->1)
// Ledger: R22 = 163.8us, issue-bound on 64 trans/step (~16 cyc each = ~1030 of
// ~1540 cyc/step). Each removed trans ~= 2us.
// R23 cell algebra: with P=(1+Ei)(1+Eg),
//   c' = [c*P + (1-Eg)(1+Ef)] / [(1+Ef)*P]        (ONE rcp for f*c + i*g)
//   h  = (1-Ec) / ((1+Eo)(1+Ec))                  (one rcp, as R22)
// -> 5 exp + 2 rcp = 7 trans/unit (was 8), +2 cheap FMAs. Clamps on the
// -2*L2E exponents keep all paths finite (no inf*0).
// Rest identical to R22: single-product f16 MFMA (8/step), K-permuted A so B
// is lane-local (k=8g+i -> W_ih[.][4g+i] | W_hh[.][4g+i-4]; D row =
// 4*(lane>>4)+q, col=lane&15), bias in C-init, L1(t)||L0(t+1) pipeline.

#define L2E 1.4426950408889634f
#define EPB 16        // elements per wave (= MFMA N)

typedef _Float16 f16x8 __attribute__((ext_vector_type(8)));
typedef float    f32x4 __attribute__((ext_vector_type(4)));

__device__ __forceinline__ float sigm(float v) {
    return __builtin_amdgcn_rcpf(1.0f + __builtin_amdgcn_exp2f(-L2E * v));
}
__device__ __forceinline__ float tanh_(float v) {
    return 1.0f - 2.0f * __builtin_amdgcn_rcpf(1.0f + __builtin_amdgcn_exp2f((2.0f * L2E) * v));
}

__device__ __forceinline__ f16x8 mk8(const _Float16* a, const _Float16* b) {
    f16x8 r;
    #pragma unroll
    for (int i = 0; i < 4; ++i) { r[i] = a[i]; r[4 + i] = b[i]; }
    return r;
}

// one layer's gates, single product: acc[m] = bias[m] + A·Bh
#define GATES1(ACC, A, BIAS, BH)                                                      \
    _Pragma("unroll")                                                                 \
    for (int m = 0; m < 4; ++m) {                                                     \
        ACC[m] = BIAS[m];                                                             \
        ACC[m] = __builtin_amdgcn_mfma_f32_16x16x32_f16(A[m], BH, ACC[m], 0, 0, 0);   \
    }

// one-rcp cell update (7 trans/unit):
//   Ei=e^-ai, Ef=e^-af, Eg=e^-2ag(cl), Eo=e^-ao; P=(1+Ei)(1+Eg)
//   c' = (c*P + (1-Eg)(1+Ef)) * rcp((1+Ef)*P)
//   Ec=e^-2c'(cl); h = (1-Ec) * rcp((1+Eo)(1+Ec))
#define COMBINE_FR(ACC, CC, HV)                                                       \
    _Pragma("unroll")                                                                 \
    for (int q = 0; q < 4; ++q) {                                                     \
        const float Ei_ = __builtin_amdgcn_exp2f(-L2E * ACC[0][q]);                   \
        const float Ef_ = __builtin_amdgcn_exp2f(-L2E * ACC[1][q]);                   \
        const float Eg_ = __builtin_amdgcn_exp2f(fmaxf(ACC[2][q], -40.0f) *           \
                                                 (-2.0f * L2E));                      \
        const float Eo_ = __builtin_amdgcn_exp2f(-L2E * ACC[3][q]);                   \
        const float fp_ = 1.0f + Ef_;                                                 \
        const float P_  = (1.0f + Ei_) * (1.0f + Eg_);                                \
        const float N_  = fmaf(CC[q], P_, (1.0f - Eg_) * fp_);                        \
        CC[q] = N_ * __builtin_amdgcn_rcpf(fp_ * P_);                                 \
        const float Ec_ = __builtin_amdgcn_exp2f(fmaxf(CC[q], -40.0f) *               \
                                                 (-2.0f * L2E));                      \
        HV[q] = (1.0f - Ec_) *                                                        \
            __builtin_amdgcn_rcpf((1.0f + Eo_) * (1.0f + Ec_));                       \
    }

__global__ __launch_bounds__(64) void lstm_fr2(
    const float* __restrict__ x,
    const float* __restrict__ w_in, const float* __restrict__ b_in,
    const float* __restrict__ w_ih0, const float* __restrict__ w_hh0,
    const float* __restrict__ b_ih0, const float* __restrict__ b_hh0,
    const float* __restrict__ w_ih1, const float* __restrict__ w_hh1,
    const float* __restrict__ b_ih1, const float* __restrict__ b_hh1,
    const float* __restrict__ fc_h_w, const float* __restrict__ fc_h_b,
    const float* __restrict__ fc_o_w, const float* __restrict__ fc_o_b,
    float* __restrict__ out, int B, int T)
{
    const int lane = threadIdx.x;        // 0..63
    const int e    = lane & 15;          // element column (= A row within tile)
    const int g    = lane >> 4;          // k-group / D-row group
    const int base = blockIdx.x * EPB;
    int rowe = base + e; if (rowe >= B) rowe = B - 1;

    __shared__ float htab[EPB][16];      // head exchange only

    // ---- A-fragments (f16 RTN), K-permuted ----
    f16x8 a0[4], a1[4];
    f32x4 bias0[4], bias1[4];
    #pragma unroll
    for (int m = 0; m < 4; ++m) {
        const int r = 16 * m + e;
        #pragma unroll
        for (int i = 0; i < 8; ++i) {
            const float w0 = (i < 4) ? w_ih0[r * 16 + 4 * g + i]
                                     : w_hh0[r * 16 + 4 * g + (i - 4)];
            const float w1 = (i < 4) ? w_ih1[r * 16 + 4 * g + i]
                                     : w_hh1[r * 16 + 4 * g + (i - 4)];
            a0[m][i] = (_Float16)w0;
            a1[m][i] = (_Float16)w1;
        }
        const int rd = 16 * m + 4 * g;
        #pragma unroll
        for (int q = 0; q < 4; ++q) {
            bias0[m][q] = b_ih0[rd + q] + b_hh0[rd + q];
            bias1[m][q] = b_ih1[rd + q] + b_hh1[rd + q];
        }
    }
    float winq[4], binq[4];
    #pragma unroll
    for (int q = 0; q < 4; ++q) { winq[q] = w_in[4 * g + q]; binq[q] = b_in[4 * g + q]; }

    // ---- state: c in f32; h as f16 (RTN) element arrays ----
    float c0[4] = {0.f, 0.f, 0.f, 0.f};
    float c1[4] = {0.f, 0.f, 0.f, 0.f};
    float h1v[4] = {0.f, 0.f, 0.f, 0.f};
    _Float16 h0h[4], h1h[4];
    #pragma unroll
    for (int q = 0; q < 4; ++q) h1h[q] = (_Float16)0.f;

    const float* xrow = x + (size_t)rowe * T;

    // ---- prologue: L0 at t=0 (h0_{-1}=0) ----
    {
        const float xv = xrow[0];
        _Float16 xh[4], zh[4];
        #pragma unroll
        for (int q = 0; q < 4; ++q) {
            xh[q] = (_Float16)fmaxf(fmaf(xv, winq[q], binq[q]), 0.0f);
            zh[q] = (_Float16)0.f;
        }
        const f16x8 Bh = mk8(xh, zh);
        f32x4 acc[4];
        GATES1(acc, a0, bias0, Bh);
        float h0v[4];
        COMBINE_FR(acc, c0, h0v);
        #pragma unroll
        for (int q = 0; q < 4; ++q) h0h[q] = (_Float16)h0v[q];
    }

    float xv1 = xrow[(T > 1) ? 1 : 0];               // x(t+1) for the loop

    // ---- steady state: iteration t does L1(t) || L0(t+1) (independent) ----
    for (int t = 0; t < T - 1; ++t) {
        const int tn = (t + 2 < T) ? (t + 2) : (T - 1);
        const float xn = xrow[tn];                   // prefetch x(t+2)

        _Float16 xh[4];
        #pragma unroll
        for (int q = 0; q < 4; ++q)
            xh[q] = (_Float16)fmaxf(fmaf(xv1, winq[q], binq[q]), 0.0f);

        const f16x8 B0h = mk8(xh, h0h);              // [xi(t+1); h0(t)]
        const f16x8 B1h = mk8(h0h, h1h);             // [h0(t); h1(t-1)]

        f32x4 acc0[4], acc1[4];
        GATES1(acc0, a0, bias0, B0h);                // L0(t+1)
        GATES1(acc1, a1, bias1, B1h);                // L1(t)

        float h0v[4];
        COMBINE_FR(acc0, c0, h0v);                   // h0(t+1)
        COMBINE_FR(acc1, c1, h1v);                   // h1(t)

        #pragma unroll
        for (int q = 0; q < 4; ++q) {
            h0h[q] = (_Float16)h0v[q];
            h1h[q] = (_Float16)h1v[q];
        }
        xv1 = xn;
    }

    // ---- epilogue: L1(T-1) from h0(T-1), h1(T-2) ----
    {
        const f16x8 Bh = mk8(h0h, h1h);
        f32x4 acc[4];
        GATES1(acc, a1, bias1, Bh);
        COMBINE_FR(acc, c1, h1v);                    // final h1
    }

    // ---- head: fc_h (16->8) + ReLU, fc_o (8->1) ----
    *(float4*)&htab[e][4 * g] = make_float4(h1v[0], h1v[1], h1v[2], h1v[3]);
    __syncthreads();
    if (lane < EPB) {
        const int ee = lane;
        float hv[16];
        #pragma unroll
        for (int k = 0; k < 16; ++k) hv[k] = htab[ee][k];
        float z[8];
        #pragma unroll
        for (int p = 0; p < 8; ++p) {
            float acc = fc_h_b[p];
            #pragma unroll
            for (int k = 0; k < 16; ++k) acc = fmaf(fc_h_w[p * 16 + k], hv[k], acc);
            z[p] = fmaxf(acc, 0.0f);
        }
        float o = fc_o_b[0];
        #pragma unroll
        for (int p = 0; p < 8; ++p) o = fmaf(fc_o_w[p], z[p], o);
        if (base + ee < B) out[base + ee] = o;
    }
}

extern "C" void kernel_launch(void* const* d_in, const int* in_sizes, int n_in,
                              void* d_out, int out_size, void* d_ws, size_t ws_size,
                              hipStream_t stream) {
    const float* x      = (const float*)d_in[0];
    const float* w_in   = (const float*)d_in[1];
    const float* b_in   = (const float*)d_in[2];
    const float* w_ih0  = (const float*)d_in[3];
    const float* w_hh0  = (const float*)d_in[4];
    const float* b_ih0  = (const float*)d_in[5];
    const float* b_hh0  = (const float*)d_in[6];
    const float* w_ih1  = (const float*)d_in[7];
    const float* w_hh1  = (const float*)d_in[8];
    const float* b_ih1  = (const float*)d_in[9];
    const float* b_hh1  = (const float*)d_in[10];
    const float* fc_h_w = (const float*)d_in[11];
    const float* fc_h_b = (const float*)d_in[12];
    const float* fc_o_w = (const float*)d_in[13];
    const float* fc_o_b = (const float*)d_in[14];

    const int B = out_size;                 // x is [B,T,1]
    const int T = in_sizes[0] / (B > 0 ? B : 1);
    const int grid = (B + EPB - 1) / EPB;   // 512 blocks at B=8192

    hipLaunchKernelGGL(lstm_fr2, dim3(grid), dim3(64), 0, stream,
                       x, w_in, b_in, w_ih0, w_hh0, b_ih0, b_hh0,
                       w_ih1, w_hh1, b_ih1, b_hh1, fc_h_w, fc_h_b,
                       fc_o_w, fc_o_b, (float*)d_out, B, T);
}

// Round 24
// 122.415 us; speedup vs baseline: 2.0915x; 1.2590x over previous
//
#include <hip/hip_runtime.h>
#include <math.h>

// LSTMLightweight on MI355X (R24 = R23 + duplicated-column MFMA, split combine).
//   x[B,T,1] -> linear_in(1->16)+ReLU -> LSTM0(16) -> LSTM1(16) -> fc(16->8)+ReLU -> fc(8->1)
// R23 (154us) ledger: step ~1445 cyc = 56 trans x 16 + ~230 VALU + 40 MFMA +
// ~250 stall; trans/unit is at the algebraic floor (5 exp + 2 rcp). The waste:
// 512 waves (B/16, pinned by MFMA N=16) occupy only 512 of 1024 SIMDs.
// R24: 8 real elements/wave with B cols DUPLICATED (col e+8 = col e) -> lane
// pairs (g,e)/(g,e+8) hold identical acc; lane e<8 combines units q={0,1},
// lane e>=8 combines q={2,3} -> 28 trans/step/lane. Halves merged with ONE
// shfl_xor(8) per layer (2 f16 h's packed per word) + selects. Grid doubles to
// 1024 one-wave blocks -> 4 waves/CU -> ALL SIMD trans pipes active.
// Numerics bit-identical to R23 (same f32 acc, f16 RTN h): absmax 0.00195.
// Math: K-permuted A so B is lane-local (k=8g+i -> W_ih[.][4g+i] |
// W_hh[.][4g+i-4]; D row=4*(lane>>4)+q, col=lane&15), one-rcp fraction cell
// (7 trans/unit), bias in C-init, L1(t) || L0(t+1) in-wave pipeline.

#define L2E 1.4426950408889634f
#define EPB 8         // REAL elements per wave/block (cols 8..15 duplicate 0..7)

typedef _Float16 f16x8 __attribute__((ext_vector_type(8)));
typedef float    f32x4 __attribute__((ext_vector_type(4)));
typedef int      i32x4 __attribute__((ext_vector_type(4)));

__device__ __forceinline__ float sigm(float v) {
    return __builtin_amdgcn_rcpf(1.0f + __builtin_amdgcn_exp2f(-L2E * v));
}

__device__ __forceinline__ unsigned pkh(float a, float b) {   // pack 2 f16 RTN
    const _Float16 ha = (_Float16)a, hb = (_Float16)b;
    return (unsigned)__builtin_bit_cast(unsigned short, ha) |
           ((unsigned)__builtin_bit_cast(unsigned short, hb) << 16);
}
__device__ __forceinline__ float unpk(unsigned w, int hi) {
    const unsigned short s = (unsigned short)(hi ? (w >> 16) : (w & 0xffffu));
    return (float)__builtin_bit_cast(_Float16, s);
}
__device__ __forceinline__ f16x8 frag4(unsigned w0, unsigned w1,
                                       unsigned w2, unsigned w3) {
    i32x4 t = {(int)w0, (int)w1, (int)w2, (int)w3};
    return __builtin_bit_cast(f16x8, t);
}

// one layer's gates, single product: acc[m] = bias[m] + A·B
#define GATES1(ACC, A, BIAS, BH)                                                      \
    _Pragma("unroll")                                                                 \
    for (int m = 0; m < 4; ++m) {                                                     \
        ACC[m] = BIAS[m];                                                             \
        ACC[m] = __builtin_amdgcn_mfma_f32_16x16x32_f16(A[m], BH, ACC[m], 0, 0, 0);   \
    }

// split combine: this lane handles 2 units (q0,q1) selected by hi8.
// one-rcp cell (7 trans/unit). Produces OWN = pkh(h_q0, h_q1); updates CA,CB.
#define COMBINE2(ACC, CA, CB, OWN)                                                    \
    do {                                                                              \
        const float aI0 = hi8 ? ACC[0][2] : ACC[0][0];                                \
        const float aI1 = hi8 ? ACC[0][3] : ACC[0][1];                                \
        const float aF0 = hi8 ? ACC[1][2] : ACC[1][0];                                \
        const float aF1 = hi8 ? ACC[1][3] : ACC[1][1];                                \
        const float aG0 = hi8 ? ACC[2][2] : ACC[2][0];                                \
        const float aG1 = hi8 ? ACC[2][3] : ACC[2][1];                                \
        const float aO0 = hi8 ? ACC[3][2] : ACC[3][0];                                \
        const float aO1 = hi8 ? ACC[3][3] : ACC[3][1];                                \
        /* unit 0 */                                                                  \
        const float Ei0 = __builtin_amdgcn_exp2f(-L2E * aI0);                         \
        const float Ef0 = __builtin_amdgcn_exp2f(-L2E * aF0);                         \
        const float Eg0 = __builtin_amdgcn_exp2f(fmaxf(aG0, -40.0f) * (-2.0f * L2E)); \
        const float Eo0 = __builtin_amdgcn_exp2f(-L2E * aO0);                         \
        const float fp0 = 1.0f + Ef0;                                                 \
        const float P0  = (1.0f + Ei0) * (1.0f + Eg0);                                \
        const float N0  = fmaf(CA, P0, (1.0f - Eg0) * fp0);                           \
        CA = N0 * __builtin_amdgcn_rcpf(fp0 * P0);                                    \
        const float Ec0 = __builtin_amdgcn_exp2f(fmaxf(CA, -40.0f) * (-2.0f * L2E));  \
        const float h0_ = (1.0f - Ec0) *                                              \
            __builtin_amdgcn_rcpf((1.0f + Eo0) * (1.0f + Ec0));                       \
        /* unit 1 */                                                                  \
        const float Ei1 = __builtin_amdgcn_exp2f(-L2E * aI1);                         \
        const float Ef1 = __builtin_amdgcn_exp2f(-L2E * aF1);                         \
        const float Eg1 = __builtin_amdgcn_exp2f(fmaxf(aG1, -40.0f) * (-2.0f * L2E)); \
        const float Eo1 = __builtin_amdgcn_exp2f(-L2E * aO1);                         \
        const float fp1 = 1.0f + Ef1;                                                 \
        const float P1  = (1.0f + Ei1) * (1.0f + Eg1);                                \
        const float N1  = fmaf(CB, P1, (1.0f - Eg1) * fp1);                           \
        CB = N1 * __builtin_amdgcn_rcpf(fp1 * P1);                                    \
        const float Ec1 = __builtin_amdgcn_exp2f(fmaxf(CB, -40.0f) * (-2.0f * L2E));  \
        const float h1_ = (1.0f - Ec1) *                                              \
            __builtin_amdgcn_rcpf((1.0f + Eo1) * (1.0f + Ec1));                       \
        OWN = pkh(h0_, h1_);                                                          \
    } while (0)

// exchange halves: lane pair (g,e)<->(g,e+8); w0 = units {4g,4g+1}, w1 = {4g+2,4g+3}
#define EXCH(OWN, W0, W1)                                                             \
    do {                                                                              \
        const unsigned oth_ = (unsigned)__shfl_xor((int)(OWN), 8, 64);                \
        W0 = hi8 ? oth_ : (OWN);                                                      \
        W1 = hi8 ? (OWN) : oth_;                                                      \
    } while (0)

__global__ __launch_bounds__(64) void lstm_dup(
    const float* __restrict__ x,
    const float* __restrict__ w_in, const float* __restrict__ b_in,
    const float* __restrict__ w_ih0, const float* __restrict__ w_hh0,
    const float* __restrict__ b_ih0, const float* __restrict__ b_hh0,
    const float* __restrict__ w_ih1, const float* __restrict__ w_hh1,
    const float* __restrict__ b_ih1, const float* __restrict__ b_hh1,
    const float* __restrict__ fc_h_w, const float* __restrict__ fc_h_b,
    const float* __restrict__ fc_o_w, const float* __restrict__ fc_o_b,
    float* __restrict__ out, int B, int T)
{
    const int lane = threadIdx.x;        // 0..63
    const int e    = lane & 15;          // B column (real elem = e&7)
    const int g    = lane >> 4;          // k-group / D-row group
    const bool hi8 = (e >= 8);
    const int base = blockIdx.x * EPB;
    int rowe = base + (e & 7); if (rowe >= B) rowe = B - 1;

    __shared__ float htab[EPB][16];      // head exchange only

    // ---- A-fragments (f16 RTN), K-permuted (A rows are gate rows — all real) ----
    f16x8 a0[4], a1[4];
    f32x4 bias0[4], bias1[4];
    #pragma unroll
    for (int m = 0; m < 4; ++m) {
        const int r = 16 * m + e;
        #pragma unroll
        for (int i = 0; i < 8; ++i) {
            const float w0 = (i < 4) ? w_ih0[r * 16 + 4 * g + i]
                                     : w_hh0[r * 16 + 4 * g + (i - 4)];
            const float w1 = (i < 4) ? w_ih1[r * 16 + 4 * g + i]
                                     : w_hh1[r * 16 + 4 * g + (i - 4)];
            a0[m][i] = (_Float16)w0;
            a1[m][i] = (_Float16)w1;
        }
        const int rd = 16 * m + 4 * g;
        #pragma unroll
        for (int q = 0; q < 4; ++q) {
            bias0[m][q] = b_ih0[rd + q] + b_hh0[rd + q];
            bias1[m][q] = b_ih1[rd + q] + b_hh1[rd + q];
        }
    }
    float winq[4], binq[4];
    #pragma unroll
    for (int q = 0; q < 4; ++q) { winq[q] = w_in[4 * g + q]; binq[q] = b_in[4 * g + q]; }

    // ---- state: this lane's 2 cells per layer; h as packed f16 words ----
    float c0A = 0.f, c0B = 0.f, c1A = 0.f, c1B = 0.f;
    unsigned h0w0, h0w1;                 // h0(t):  units {4g,4g+1}, {4g+2,4g+3}
    unsigned h1w0 = 0u, h1w1 = 0u;       // h1(t-1)
    unsigned h1own = 0u;                 // last L1 own-pack (for head)

    const float* xrow = x + (size_t)rowe * T;

    // ---- prologue: L0 at t=0 (h0_{-1}=0) ----
    {
        const float xv = xrow[0];
        const unsigned xw0 = pkh(fmaxf(fmaf(xv, winq[0], binq[0]), 0.0f),
                                 fmaxf(fmaf(xv, winq[1], binq[1]), 0.0f));
        const unsigned xw1 = pkh(fmaxf(fmaf(xv, winq[2], binq[2]), 0.0f),
                                 fmaxf(fmaf(xv, winq[3], binq[3]), 0.0f));
        const f16x8 Bh = frag4(xw0, xw1, 0u, 0u);
        f32x4 acc[4];
        GATES1(acc, a0, bias0, Bh);
        unsigned own;
        COMBINE2(acc, c0A, c0B, own);
        EXCH(own, h0w0, h0w1);
    }

    float xv1 = xrow[(T > 1) ? 1 : 0];               // x(t+1) for the loop

    // ---- steady state: iteration t does L1(t) || L0(t+1) (independent) ----
    for (int t = 0; t < T - 1; ++t) {
        const int tn = (t + 2 < T) ? (t + 2) : (T - 1);
        const float xn = xrow[tn];                   // prefetch x(t+2)

        const unsigned xw0 = pkh(fmaxf(fmaf(xv1, winq[0], binq[0]), 0.0f),
                                 fmaxf(fmaf(xv1, winq[1], binq[1]), 0.0f));
        const unsigned xw1 = pkh(fmaxf(fmaf(xv1, winq[2], binq[2]), 0.0f),
                                 fmaxf(fmaf(xv1, winq[3], binq[3]), 0.0f));

        const f16x8 B0h = frag4(xw0, xw1, h0w0, h0w1);   // [xi(t+1); h0(t)]
        const f16x8 B1h = frag4(h0w0, h0w1, h1w0, h1w1); // [h0(t); h1(t-1)]

        f32x4 acc0[4], acc1[4];
        GATES1(acc0, a0, bias0, B0h);                // L0(t+1)
        GATES1(acc1, a1, bias1, B1h);                // L1(t)

        unsigned own0, own1;
        COMBINE2(acc0, c0A, c0B, own0);              // h0(t+1) halves
        COMBINE2(acc1, c1A, c1B, own1);              // h1(t) halves

        EXCH(own0, h0w0, h0w1);
        EXCH(own1, h1w0, h1w1);
        h1own = own1;
        xv1 = xn;
    }

    // ---- epilogue: L1(T-1) from h0(T-1), h1(T-2) ----
    {
        const f16x8 Bh = frag4(h0w0, h0w1, h1w0, h1w1);
        f32x4 acc[4];
        GATES1(acc, a1, bias1, Bh);
        unsigned own;
        COMBINE2(acc, c1A, c1B, own);
        EXCH(own, h1w0, h1w1);
        h1own = own;
        (void)h1own;
    }

    // ---- head: write final h1 (lanes e<8 hold both words after EXCH) ----
    if (!hi8) {
        htab[e][4 * g + 0] = unpk(h1w0, 0);
        htab[e][4 * g + 1] = unpk(h1w0, 1);
        htab[e][4 * g + 2] = unpk(h1w1, 0);
        htab[e][4 * g + 3] = unpk(h1w1, 1);
    }
    __syncthreads();
    if (lane < EPB) {
        const int ee = lane;
        float hv[16];
        #pragma unroll
        for (int k = 0; k < 16; ++k) hv[k] = htab[ee][k];
        float z[8];
        #pragma unroll
        for (int p = 0; p < 8; ++p) {
            float acc = fc_h_b[p];
            #pragma unroll
            for (int k = 0; k < 16; ++k) acc = fmaf(fc_h_w[p * 16 + k], hv[k], acc);
            z[p] = fmaxf(acc, 0.0f);
        }
        float o = fc_o_b[0];
        #pragma unroll
        for (int p = 0; p < 8; ++p) o = fmaf(fc_o_w[p], z[p], o);
        if (base + ee < B) out[base + ee] = o;
    }
}

extern "C" void kernel_launch(void* const* d_in, const int* in_sizes, int n_in,
                              void* d_out, int out_size, void* d_ws, size_t ws_size,
                              hipStream_t stream) {
    const float* x      = (const float*)d_in[0];
    const float* w_in   = (const float*)d_in[1];
    const float* b_in   = (const float*)d_in[2];
    const float* w_ih0  = (const float*)d_in[3];
    const float* w_hh0  = (const float*)d_in[4];
    const float* b_ih0  = (const float*)d_in[5];
    const float* b_hh0  = (const float*)d_in[6];
    const float* w_ih1  = (const float*)d_in[7];
    const float* w_hh1  = (const float*)d_in[8];
    const float* b_ih1  = (const float*)d_in[9];
    const float* b_hh1  = (const float*)d_in[10];
    const float* fc_h_w = (const float*)d_in[11];
    const float* fc_h_b = (const float*)d_in[12];
    const float* fc_o_w = (const float*)d_in[13];
    const float* fc_o_b = (const float*)d_in[14];

    const int B = out_size;                 // x is [B,T,1]
    const int T = in_sizes[0] / (B > 0 ? B : 1);
    const int grid = (B + EPB - 1) / EPB;   // 1024 blocks at B=8192

    hipLaunchKernelGGL(lstm_dup, dim3(grid), dim3(64), 0, stream,
                       x, w_in, b_in, w_ih0, w_hh0, b_ih0, b_hh0,
                       w_ih1, w_hh1, b_ih1, b_hh1, fc_h_w, fc_h_b,
                       fc_o_w, fc_o_b, (float*)d_out, B, T);
}